// Round 1
// baseline (158.868 us; speedup 1.0000x reference)
//
#include <hip/hip_runtime.h>
#include <hip/hip_bf16.h>

#define HH 224
#define WW 224
#define HWPIX (HH * WW)

__global__ __launch_bounds__(256) void Bilinear_48232482734312_kernel(
    const float* __restrict__ x, float* __restrict__ out, int total) {
    int idx = blockIdx.x * blockDim.x + threadIdx.x;
    if (idx >= total) return;

    int b = idx / HWPIX;

    const float* px = x + (size_t)idx * 5;
    float X = px[3];
    float Y = px[4];

    float fx = floorf(X);
    float fy = floorf(Y);
    float wx = X - fx;
    float wy = Y - fy;

    // padded-image indices, clipped to [0, 224]; -1 -> original image coords
    float fXf = fminf(fmaxf(fx + 1.0f, 0.0f), (float)WW);
    float cXf = fminf(fmaxf(fx + 2.0f, 0.0f), (float)WW);
    float fYf = fminf(fmaxf(fy + 1.0f, 0.0f), (float)HH);
    float cYf = fminf(fmaxf(fy + 2.0f, 0.0f), (float)HH);
    int x0 = (int)fXf - 1;
    int x1 = (int)cXf - 1;
    int y0 = (int)fYf - 1;
    int y1 = (int)cYf - 1;

    const float* imgb = x + (size_t)b * HWPIX * 5;

    float tl0 = 0.f, tl1 = 0.f, tl2 = 0.f;
    float bl0 = 0.f, bl1 = 0.f, bl2 = 0.f;
    float tr0 = 0.f, tr1 = 0.f, tr2 = 0.f;
    float br0 = 0.f, br1 = 0.f, br2 = 0.f;

    if (y0 >= 0 && x0 >= 0) {
        const float* p = imgb + ((size_t)y0 * WW + x0) * 5;
        tl0 = p[0]; tl1 = p[1]; tl2 = p[2];
    }
    if (y1 >= 0 && x0 >= 0) {
        const float* p = imgb + ((size_t)y1 * WW + x0) * 5;
        bl0 = p[0]; bl1 = p[1]; bl2 = p[2];
    }
    if (y0 >= 0 && x1 >= 0) {
        const float* p = imgb + ((size_t)y0 * WW + x1) * 5;
        tr0 = p[0]; tr1 = p[1]; tr2 = p[2];
    }
    if (y1 >= 0 && x1 >= 0) {
        const float* p = imgb + ((size_t)y1 * WW + x1) * 5;
        br0 = p[0]; br1 = p[1]; br2 = p[2];
    }

    float wtl = (1.0f - wx) * (1.0f - wy);
    float wbl = (1.0f - wx) * wy;
    float wtr = wx * (1.0f - wy);
    float wbr = wx * wy;

    float* o = out + (size_t)idx * 3;
    o[0] = wtl * tl0 + wbl * bl0 + wtr * tr0 + wbr * br0;
    o[1] = wtl * tl1 + wbl * bl1 + wtr * tr1 + wbr * br1;
    o[2] = wtl * tl2 + wbl * bl2 + wtr * tr2 + wbr * br2;
}

extern "C" void kernel_launch(void* const* d_in, const int* in_sizes, int n_in,
                              void* d_out, int out_size, void* d_ws, size_t ws_size,
                              hipStream_t stream) {
    const float* x = (const float*)d_in[0];
    float* out = (float*)d_out;
    int total = in_sizes[0] / 5;  // B*H*W pixels
    int block = 256;
    int grid = (total + block - 1) / block;
    Bilinear_48232482734312_kernel<<<grid, block, 0, stream>>>(x, out, total);
}

// Round 2
// 113.515 us; speedup vs baseline: 1.3995x; 1.3995x over previous
//
#include <hip/hip_runtime.h>
#include <hip/hip_bf16.h>

#define HH 224
#define WW 224
#define HWPIX (HH * WW)          // 50176 = 196 * 256
#define BLOCKS_PER_IMG 196
#define NXCD 8

__global__ __launch_bounds__(256) void Bilinear_48232482734312_kernel(
    const float* __restrict__ x, float* __restrict__ out, int n_img) {
    // XCD-aware swizzle: hardware round-robins consecutive blockIdx across the
    // 8 XCDs. Map block b (on XCD b%8) to image ≡ b%8 (mod 8) so each image's
    // 196 blocks run on ONE XCD -> its 1 MB img panel lives in that XCD's 4 MiB
    // L2 and gathers stop duplicating fetches across XCDs.
    int wg = blockIdx.x;
    int xcd = wg & (NXCD - 1);
    int slot = wg >> 3;                    // 0 .. n_img/8*196-1
    int img_group = slot / BLOCKS_PER_IMG;
    int blk = slot - img_group * BLOCKS_PER_IMG;
    int img = img_group * NXCD + xcd;
    if (img >= n_img) return;

    size_t idx = (size_t)img * HWPIX + blk * 256 + threadIdx.x;

    const float* px = x + idx * 5;
    float X = px[3];
    float Y = px[4];

    float fx = floorf(X);
    float fy = floorf(Y);
    float wx = X - fx;
    float wy = Y - fy;

    // Branch-free clamped indices. Equivalent to the reference's
    // clip-into-padded for all reachable inputs (X,Y >= 0): clip at 224 maps
    // to img col/row 223; the zero-pad is only addressable for X<0 / Y<0.
    int x0 = min(max((int)fx,     0), WW - 1);
    int x1 = min(max((int)fx + 1, 0), WW - 1);
    int y0 = min(max((int)fy,     0), HH - 1);
    int y1 = min(max((int)fy + 1, 0), HH - 1);

    const float* imgb = x + (size_t)img * HWPIX * 5;
    const float* ptl = imgb + ((size_t)y0 * WW + x0) * 5;
    const float* pbl = imgb + ((size_t)y1 * WW + x0) * 5;
    const float* ptr = imgb + ((size_t)y0 * WW + x1) * 5;
    const float* pbr = imgb + ((size_t)y1 * WW + x1) * 5;

    // Issue all 4 gathers before any use so they overlap.
    float tl0 = ptl[0], tl1 = ptl[1], tl2 = ptl[2];
    float bl0 = pbl[0], bl1 = pbl[1], bl2 = pbl[2];
    float tr0 = ptr[0], tr1 = ptr[1], tr2 = ptr[2];
    float br0 = pbr[0], br1 = pbr[1], br2 = pbr[2];

    float wtl = (1.0f - wx) * (1.0f - wy);
    float wbl = (1.0f - wx) * wy;
    float wtr = wx * (1.0f - wy);
    float wbr = wx * wy;

    float* o = out + idx * 3;
    o[0] = wtl * tl0 + wbl * bl0 + wtr * tr0 + wbr * br0;
    o[1] = wtl * tl1 + wbl * bl1 + wtr * tr1 + wbr * br1;
    o[2] = wtl * tl2 + wbl * bl2 + wtr * tr2 + wbr * br2;
}

extern "C" void kernel_launch(void* const* d_in, const int* in_sizes, int n_in,
                              void* d_out, int out_size, void* d_ws, size_t ws_size,
                              hipStream_t stream) {
    const float* x = (const float*)d_in[0];
    float* out = (float*)d_out;
    int total = in_sizes[0] / 5;           // B*H*W pixels
    int n_img = total / HWPIX;             // 128
    // round images up to a multiple of NXCD for the swizzle arithmetic
    int n_img_pad = (n_img + NXCD - 1) & ~(NXCD - 1);
    int grid = n_img_pad * BLOCKS_PER_IMG;
    Bilinear_48232482734312_kernel<<<grid, 256, 0, stream>>>(x, out, n_img);
}

// Round 3
// 98.142 us; speedup vs baseline: 1.6188x; 1.1566x over previous
//
#include <hip/hip_runtime.h>
#include <hip/hip_bf16.h>

#define HH 224
#define WW 224
#define HWPIX (HH * WW)          // 50176 = 196 * 256
#define BLOCKS_PER_IMG 196
#define NXCD 8

// 4B-aligned vector types: pixel stride is 20B, so 16B/8B loads are only
// dword-aligned. gfx950 supports unaligned global access; aligned(4) keeps
// the compiler honest while still emitting dwordx4/dwordx2.
typedef float f4 __attribute__((ext_vector_type(4), aligned(4)));
typedef float f2 __attribute__((ext_vector_type(2), aligned(4)));

__global__ __launch_bounds__(256) void Bilinear_48232482734312_kernel(
    const float* __restrict__ x, float* __restrict__ out, int n_img) {
    // XCD-aware swizzle: consecutive blockIdx round-robin across 8 XCDs; map
    // so each image's 196 blocks land on ONE XCD -> img panel (1 MB) stays in
    // that XCD's 4 MiB L2.
    int wg = blockIdx.x;
    int xcd = wg & (NXCD - 1);
    int slot = wg >> 3;
    int img_group = slot / BLOCKS_PER_IMG;
    int blk = slot - img_group * BLOCKS_PER_IMG;
    int img = img_group * NXCD + xcd;
    if (img >= n_img) return;

    size_t idx = (size_t)img * HWPIX + blk * 256 + threadIdx.x;

    // one dwordx2 for the coords (offsets 3,4 in the 5-float pixel)
    f2 xy = *(const f2*)(x + idx * 5 + 3);
    float X = xy.x;
    float Y = xy.y;

    float fx = floorf(X);
    float fy = floorf(Y);
    float wx = X - fx;
    float wy = Y - fy;

    // Branch-free clamped indices (equivalent to reference clip for X,Y >= 0).
    int x0 = min(max((int)fx,     0), WW - 1);
    int x1 = min(max((int)fx + 1, 0), WW - 1);
    int y0 = min(max((int)fy,     0), HH - 1);
    int y1 = min(max((int)fy + 1, 0), HH - 1);

    const float* imgb = x + (size_t)img * HWPIX * 5;
    const float* r0 = imgb + (size_t)y0 * (WW * 5);
    const float* r1 = imgb + (size_t)y1 * (WW * 5);

    // 4 divergent gathers, one dwordx4 each (RGB + 1 dead lane), all issued
    // before any use so they overlap.
    f4 tl = *(const f4*)(r0 + x0 * 5);
    f4 tr = *(const f4*)(r0 + x1 * 5);
    f4 bl = *(const f4*)(r1 + x0 * 5);
    f4 br = *(const f4*)(r1 + x1 * 5);

    float wtl = (1.0f - wx) * (1.0f - wy);
    float wbl = (1.0f - wx) * wy;
    float wtr = wx * (1.0f - wy);
    float wbr = wx * wy;

    float o0 = wtl * tl.x + wbl * bl.x + wtr * tr.x + wbr * br.x;
    float o1 = wtl * tl.y + wbl * bl.y + wtr * tr.y + wbr * br.y;
    float o2 = wtl * tl.z + wbl * bl.z + wtr * tr.z + wbr * br.z;

    float* o = out + idx * 3;
    *(f2*)o = (f2){o0, o1};
    o[2] = o2;
}

extern "C" void kernel_launch(void* const* d_in, const int* in_sizes, int n_in,
                              void* d_out, int out_size, void* d_ws, size_t ws_size,
                              hipStream_t stream) {
    const float* x = (const float*)d_in[0];
    float* out = (float*)d_out;
    int total = in_sizes[0] / 5;           // B*H*W pixels
    int n_img = total / HWPIX;             // 128
    int n_img_pad = (n_img + NXCD - 1) & ~(NXCD - 1);
    int grid = n_img_pad * BLOCKS_PER_IMG;
    Bilinear_48232482734312_kernel<<<grid, 256, 0, stream>>>(x, out, n_img);
}